// Round 4
// baseline (2424.206 us; speedup 1.0000x reference)
//
#include <hip/hip_runtime.h>
#include <cmath>

// IPOT solver: n=32768 rows, K=512 cols, 20 iterations.
// Structure: init (exp(2C) -> bf16 Kb in 2nd half of d_out, 32 MB) ->
// 19 mid passes over bf16 Kb (row-dot + column partial sums, atomics into
// 8 shadow buffers, ticket-elected last block finalizes sigma_{t+1}) ->
// final pass recomputes exp(2C) from fp32 C and writes Q*n.
//
// ws float layout: [0]=ticket | [64..64+20*512)=gsig | shadows[2][8][512]

namespace {
constexpr int ROWS = 32768;
constexpr int COLS = 512;
constexpr int ITERS = 20;
constexpr float EPS = 1e-12f;
constexpr float A_M = 1.0f / 32768.0f;
constexpr float B_M = 1.0f / 512.0f;
constexpr float L2E2 = 2.8853900817779268f;  // 2/ln(2): exp(2c)=exp2(c*L2E2)
constexpr int BLOCKS = 2048;                 // 8 blocks/CU
constexpr int WPB = 4;
constexpr int TW = BLOCKS * WPB;             // 8192 waves
constexpr int RPW = ROWS / TW;               // 4 rows per wave
constexpr int NSH = 8;                       // shadow buffers
constexpr int TICKET_OFF = 0;
constexpr int GSIG_OFF = 64;
constexpr int SH_OFF = GSIG_OFF + ITERS * COLS;
constexpr int SH_SZ = NSH * COLS;
}

__device__ __forceinline__ float bflo(unsigned u) {
  union { unsigned i; float f; } v; v.i = u << 16; return v.f;
}
__device__ __forceinline__ float bfhi(unsigned u) {
  union { unsigned i; float f; } v; v.i = u & 0xFFFF0000u; return v.f;
}
__device__ __forceinline__ unsigned short f2bf(float f) {
  union { float f; unsigned u; } v; v.f = f;
  return (unsigned short)((v.u + 0x7FFFu + ((v.u >> 16) & 1u)) >> 16);
}

// ---- init: Kb = bf16(exp(2C)); gsig[0]=1/K; ticket=0; shadow buf0 = 0 ----
__global__ __launch_bounds__(256) void ipot_init_kernel(
    const float* __restrict__ C, float* __restrict__ out,
    float* __restrict__ ws) {
  const size_t stride = (size_t)gridDim.x * blockDim.x;
  const size_t gtid = (size_t)blockIdx.x * blockDim.x + threadIdx.x;
  const float4* c4 = (const float4*)C;
  ushort4* k4 = (ushort4*)(out + (size_t)ROWS * COLS / 2);
  const size_t n4 = (size_t)ROWS * COLS / 4;
  for (size_t i = gtid; i < n4; i += stride) {
    float4 c = c4[i];
    ushort4 k;
    k.x = f2bf(exp2f(c.x * L2E2));
    k.y = f2bf(exp2f(c.y * L2E2));
    k.z = f2bf(exp2f(c.z * L2E2));
    k.w = f2bf(exp2f(c.w * L2E2));
    k4[i] = k;
  }
  if (gtid < COLS) ws[GSIG_OFF + gtid] = B_M;
  if (gtid == 0) *(unsigned*)(ws + TICKET_OFF) = 0u;
  if (gtid < SH_SZ) ws[SH_OFF + gtid] = 0.0f;
}

// ---- mid pass t (t=0..18): uses bf16 Kb; accumulates tsum; finalizes sigma ----
__global__ __launch_bounds__(256, 8) void ipot_mid_kernel(
    const float* __restrict__ out_as_in, float* __restrict__ ws, int t) {
  __shared__ float sig[COLS];
  __shared__ float part[4][COLS];
  __shared__ unsigned lastv;
  const int tid = threadIdx.x;
  const int wave = tid >> 6;
  const int lane = tid & 63;

  if (t == 0) {
    sig[tid] = B_M;
    sig[tid + 256] = B_M;
  } else {
    const float* gs = ws + GSIG_OFF + (size_t)t * COLS;
    sig[tid] = gs[tid];
    sig[tid + 256] = gs[tid + 256];
  }
  __syncthreads();

  // lane covers cols [8*lane .. 8*lane+7]
  const float4 sA = *(const float4*)&sig[8 * lane];
  const float4 sB = *(const float4*)&sig[8 * lane + 4];
  const int gw = blockIdx.x * WPB + wave;
  const unsigned short* Kb =
      (const unsigned short*)(out_as_in + (size_t)ROWS * COLS / 2);

  // load all RPW rows up front (independent 16B loads in flight)
  uint4 kr[RPW];
#pragma unroll
  for (int r = 0; r < RPW; ++r) {
    const uint4* rp = (const uint4*)(Kb + (size_t)(gw + r * TW) * COLS);
    kr[r] = rp[lane];
  }

  float p[RPW];
#pragma unroll
  for (int r = 0; r < RPW; ++r) {
    p[r] = bflo(kr[r].x) * sA.x + bfhi(kr[r].x) * sA.y +
           bflo(kr[r].y) * sA.z + bfhi(kr[r].y) * sA.w +
           bflo(kr[r].z) * sB.x + bfhi(kr[r].z) * sB.y +
           bflo(kr[r].w) * sB.z + bfhi(kr[r].w) * sB.w;
  }
#pragma unroll
  for (int off = 32; off; off >>= 1) {
#pragma unroll
    for (int r = 0; r < RPW; ++r) p[r] += __shfl_xor(p[r], off, 64);
  }

  float a[8] = {0.f, 0.f, 0.f, 0.f, 0.f, 0.f, 0.f, 0.f};
#pragma unroll
  for (int r = 0; r < RPW; ++r) {
    const float inv = 1.0f / (p[r] + EPS);
    a[0] += bflo(kr[r].x) * inv; a[1] += bfhi(kr[r].x) * inv;
    a[2] += bflo(kr[r].y) * inv; a[3] += bfhi(kr[r].y) * inv;
    a[4] += bflo(kr[r].z) * inv; a[5] += bfhi(kr[r].z) * inv;
    a[6] += bflo(kr[r].w) * inv; a[7] += bfhi(kr[r].w) * inv;
  }
  *(float4*)&part[wave][8 * lane] = *(float4*)&a[0];
  *(float4*)&part[wave][8 * lane + 4] = *(float4*)&a[4];
  __syncthreads();

  float* sh = ws + SH_OFF + (size_t)(t & 1) * SH_SZ +
              (size_t)(blockIdx.x & (NSH - 1)) * COLS;
  {
    int j = tid;
    atomicAdd(&sh[j], part[0][j] + part[1][j] + part[2][j] + part[3][j]);
    j += 256;
    atomicAdd(&sh[j], part[0][j] + part[1][j] + part[2][j] + part[3][j]);
  }

  // ticket: last block finalizes sigma_{t+1} and zeroes the other shadow buf
  __threadfence();
  if (tid == 0) lastv = atomicAdd((unsigned*)(ws + TICKET_OFF), 1u);
  __syncthreads();
  if (lastv == gridDim.x - 1) {
    if (tid == 0) *(unsigned*)(ws + TICKET_OFF) = 0u;
    __threadfence();
    const float* shb = ws + SH_OFF + (size_t)(t & 1) * SH_SZ;
    float* gs_next = ws + GSIG_OFF + (size_t)(t + 1) * COLS;
    for (int j = tid; j < COLS; j += 256) {
      float T = 0.0f;
#pragma unroll
      for (int s = 0; s < NSH; ++s) T += shb[s * COLS + j];
      gs_next[j] = B_M / (sig[j] * A_M * T + EPS);
    }
    float* shn = ws + SH_OFF + (size_t)((t + 1) & 1) * SH_SZ;
    for (int i = tid; i < SH_SZ; i += 256) shn[i] = 0.0f;
  }
}

// ---- final pass: recompute exp(2C) fp32, write Q*n = K*sigma/(r+eps) ----
__global__ __launch_bounds__(256, 4) void ipot_final_kernel(
    const float* __restrict__ C, float* __restrict__ out,
    const float* __restrict__ ws) {
  __shared__ float sig[COLS];
  const int tid = threadIdx.x;
  const int wave = tid >> 6;
  const int lane = tid & 63;
  const float* gs = ws + GSIG_OFF + (size_t)(ITERS - 1) * COLS;
  sig[tid] = gs[tid];
  sig[tid + 256] = gs[tid + 256];
  __syncthreads();

  const float4 sA = *(const float4*)&sig[8 * lane];
  const float4 sB = *(const float4*)&sig[8 * lane + 4];
  const int gw = blockIdx.x * WPB + wave;

#pragma unroll
  for (int r = 0; r < RPW; ++r) {
    const int row = gw + r * TW;
    const float4* rp = (const float4*)(C + (size_t)row * COLS);
    float4 c0 = rp[2 * lane];
    float4 c1 = rp[2 * lane + 1];
    float e[8];
    e[0] = exp2f(c0.x * L2E2); e[1] = exp2f(c0.y * L2E2);
    e[2] = exp2f(c0.z * L2E2); e[3] = exp2f(c0.w * L2E2);
    e[4] = exp2f(c1.x * L2E2); e[5] = exp2f(c1.y * L2E2);
    e[6] = exp2f(c1.z * L2E2); e[7] = exp2f(c1.w * L2E2);
    float p = e[0] * sA.x + e[1] * sA.y + e[2] * sA.z + e[3] * sA.w +
              e[4] * sB.x + e[5] * sB.y + e[6] * sB.z + e[7] * sB.w;
#pragma unroll
    for (int off = 32; off; off >>= 1) p += __shfl_xor(p, off, 64);
    const float inv = 1.0f / (p + EPS);
    float4* wp = (float4*)(out + (size_t)row * COLS);
    float4 o0, o1;
    o0.x = e[0] * sA.x * inv; o0.y = e[1] * sA.y * inv;
    o0.z = e[2] * sA.z * inv; o0.w = e[3] * sA.w * inv;
    o1.x = e[4] * sB.x * inv; o1.y = e[5] * sB.y * inv;
    o1.z = e[6] * sB.z * inv; o1.w = e[7] * sB.w * inv;
    wp[2 * lane] = o0;
    wp[2 * lane + 1] = o1;
  }
}

extern "C" void kernel_launch(void* const* d_in, const int* in_sizes, int n_in,
                              void* d_out, int out_size, void* d_ws, size_t ws_size,
                              hipStream_t stream) {
  const float* C = (const float*)d_in[0];
  float* out = (float*)d_out;
  float* ws = (float*)d_ws;

  ipot_init_kernel<<<BLOCKS, 256, 0, stream>>>(C, out, ws);
  for (int t = 0; t < ITERS - 1; ++t)
    ipot_mid_kernel<<<BLOCKS, 256, 0, stream>>>(out, ws, t);
  ipot_final_kernel<<<BLOCKS, 256, 0, stream>>>(C, out, ws);
}

// Round 5
// 303.310 us; speedup vs baseline: 7.9925x; 7.9925x over previous
//
#include <hip/hip_runtime.h>
#include <cmath>

// IPOT solver: n=32768 rows, K=512 cols, 20 iterations.
// zero -> fused(exp(2C)->bf16 Kb + iteration 0) -> 18 mid passes (bf16) ->
// final pass (fp32 exp recompute, writes Q*n).
// Sigma ordering: pass t's preamble recomputes sigma_t redundantly per block
// from gsig[t-1] + tsum[t-1]; block 0 persists gsig[t]. Kernel boundaries
// order everything — NO fences, NO tickets (round-4 lesson: a per-pass
// threadfence + single-address ticket atomic cost ~120 us/pass).
//
// ws float layout: gsig[20][512] | tsum[19][ns][512]   (ns = power of 2)

namespace {
constexpr int ROWS = 32768;
constexpr int COLS = 512;
constexpr int ITERS = 20;
constexpr float EPS = 1e-12f;
constexpr float A_M = 1.0f / 32768.0f;
constexpr float B_M = 1.0f / 512.0f;
constexpr float L2E2 = 2.8853900817779268f;  // 2/ln2: exp(2c)=exp2(c*L2E2)
constexpr int BLOCKS = 2048;                 // 8 blocks/CU
constexpr int WPB = 4;
constexpr int TW = BLOCKS * WPB;             // 8192 waves
constexpr int RPW = ROWS / TW;               // 4 rows per wave
constexpr int GSIG_OFF = 0;
constexpr int TSUM_OFF = ITERS * COLS;
}

__device__ __forceinline__ float bflo(unsigned u) {
  union { unsigned i; float f; } v; v.i = u << 16; return v.f;
}
__device__ __forceinline__ float bfhi(unsigned u) {
  union { unsigned i; float f; } v; v.i = u & 0xFFFF0000u; return v.f;
}
__device__ __forceinline__ unsigned f2bf(float f) {
  union { float f; unsigned u; } v; v.f = f;
  return (v.u + 0x7FFFu + ((v.u >> 16) & 1u)) >> 16;
}

// ---- zero: gsig[0] = 1/K; zero all tsum buffers ----
__global__ __launch_bounds__(256) void ipot_zero_kernel(float* __restrict__ ws,
                                                        int ns) {
  const size_t stride = (size_t)gridDim.x * blockDim.x;
  const size_t gtid = (size_t)blockIdx.x * blockDim.x + threadIdx.x;
  if (gtid < COLS) ws[GSIG_OFF + gtid] = B_M;
  const size_t tsz = (size_t)(ITERS - 1) * ns * COLS;
  for (size_t i = gtid; i < tsz; i += stride) ws[TSUM_OFF + i] = 0.0f;
}

// ---- fused: Kb = bf16(exp(2C)) AND iteration 0 (sigma0 uniform) ----
__global__ __launch_bounds__(256, 4) void ipot_pass0_kernel(
    const float* __restrict__ C, float* __restrict__ out,
    float* __restrict__ ws, int ns) {
  __shared__ float part[4][COLS];
  const int tid = threadIdx.x;
  const int wave = tid >> 6;
  const int lane = tid & 63;
  const int gw = blockIdx.x * WPB + wave;
  unsigned short* Kb = (unsigned short*)(out + (size_t)ROWS * COLS / 2);

  float4 c0[RPW], c1[RPW];
#pragma unroll
  for (int r = 0; r < RPW; ++r) {
    const float4* rp = (const float4*)(C + (size_t)(gw + r * TW) * COLS);
    c0[r] = rp[2 * lane];
    c1[r] = rp[2 * lane + 1];
  }

  float e[RPW][8];
  float p[RPW];
#pragma unroll
  for (int r = 0; r < RPW; ++r) {
    e[r][0] = exp2f(c0[r].x * L2E2); e[r][1] = exp2f(c0[r].y * L2E2);
    e[r][2] = exp2f(c0[r].z * L2E2); e[r][3] = exp2f(c0[r].w * L2E2);
    e[r][4] = exp2f(c1[r].x * L2E2); e[r][5] = exp2f(c1[r].y * L2E2);
    e[r][6] = exp2f(c1[r].z * L2E2); e[r][7] = exp2f(c1[r].w * L2E2);
    uint4 kp;
    kp.x = f2bf(e[r][0]) | (f2bf(e[r][1]) << 16);
    kp.y = f2bf(e[r][2]) | (f2bf(e[r][3]) << 16);
    kp.z = f2bf(e[r][4]) | (f2bf(e[r][5]) << 16);
    kp.w = f2bf(e[r][6]) | (f2bf(e[r][7]) << 16);
    ((uint4*)(Kb + (size_t)(gw + r * TW) * COLS))[lane] = kp;
    p[r] = ((e[r][0] + e[r][1]) + (e[r][2] + e[r][3])) +
           ((e[r][4] + e[r][5]) + (e[r][6] + e[r][7]));
  }
#pragma unroll
  for (int off = 32; off; off >>= 1) {
#pragma unroll
    for (int r = 0; r < RPW; ++r) p[r] += __shfl_xor(p[r], off, 64);
  }
  float a[8] = {0.f, 0.f, 0.f, 0.f, 0.f, 0.f, 0.f, 0.f};
#pragma unroll
  for (int r = 0; r < RPW; ++r) {
    const float inv = 1.0f / (B_M * p[r] + EPS);  // r_i = B*sum(e)
#pragma unroll
    for (int j = 0; j < 8; ++j) a[j] += e[r][j] * inv;
  }
  *(float4*)&part[wave][8 * lane] = *(float4*)&a[0];
  *(float4*)&part[wave][8 * lane + 4] = *(float4*)&a[4];
  __syncthreads();
  float* ts = ws + TSUM_OFF + (size_t)(blockIdx.x & (ns - 1)) * COLS;
  int j = tid;
  atomicAdd(&ts[j], part[0][j] + part[1][j] + part[2][j] + part[3][j]);
  j += 256;
  atomicAdd(&ts[j], part[0][j] + part[1][j] + part[2][j] + part[3][j]);
}

// ---- mid pass t (t=1..18): preamble sigma_t, stream bf16 Kb, tsum[t] ----
__global__ __launch_bounds__(256, 8) void ipot_mid_kernel(
    const float* __restrict__ out_as_in, float* __restrict__ ws, int t,
    int ns) {
  __shared__ float sig[COLS];
  __shared__ float part[4][COLS];
  const int tid = threadIdx.x;
  const int wave = tid >> 6;
  const int lane = tid & 63;

  {
    const float* gsp = ws + GSIG_OFF + (size_t)(t - 1) * COLS;
    float* gsc = ws + GSIG_OFF + (size_t)t * COLS;
    const float* tb = ws + TSUM_OFF + (size_t)(t - 1) * ns * COLS;
    for (int j = tid; j < COLS; j += 256) {
      float T = 0.0f;
      for (int s = 0; s < ns; ++s) T += tb[s * COLS + j];
      const float sv = B_M / (gsp[j] * A_M * T + EPS);
      sig[j] = sv;
      if (blockIdx.x == 0) gsc[j] = sv;
    }
  }
  __syncthreads();

  const float4 sA = *(const float4*)&sig[8 * lane];
  const float4 sB = *(const float4*)&sig[8 * lane + 4];
  const int gw = blockIdx.x * WPB + wave;
  const unsigned short* Kb =
      (const unsigned short*)(out_as_in + (size_t)ROWS * COLS / 2);

  uint4 kr[RPW];
#pragma unroll
  for (int r = 0; r < RPW; ++r)
    kr[r] = ((const uint4*)(Kb + (size_t)(gw + r * TW) * COLS))[lane];

  float p[RPW];
#pragma unroll
  for (int r = 0; r < RPW; ++r) {
    p[r] = bflo(kr[r].x) * sA.x + bfhi(kr[r].x) * sA.y +
           bflo(kr[r].y) * sA.z + bfhi(kr[r].y) * sA.w +
           bflo(kr[r].z) * sB.x + bfhi(kr[r].z) * sB.y +
           bflo(kr[r].w) * sB.z + bfhi(kr[r].w) * sB.w;
  }
#pragma unroll
  for (int off = 32; off; off >>= 1) {
#pragma unroll
    for (int r = 0; r < RPW; ++r) p[r] += __shfl_xor(p[r], off, 64);
  }
  float a[8] = {0.f, 0.f, 0.f, 0.f, 0.f, 0.f, 0.f, 0.f};
#pragma unroll
  for (int r = 0; r < RPW; ++r) {
    const float inv = 1.0f / (p[r] + EPS);
    a[0] += bflo(kr[r].x) * inv; a[1] += bfhi(kr[r].x) * inv;
    a[2] += bflo(kr[r].y) * inv; a[3] += bfhi(kr[r].y) * inv;
    a[4] += bflo(kr[r].z) * inv; a[5] += bfhi(kr[r].z) * inv;
    a[6] += bflo(kr[r].w) * inv; a[7] += bfhi(kr[r].w) * inv;
  }
  *(float4*)&part[wave][8 * lane] = *(float4*)&a[0];
  *(float4*)&part[wave][8 * lane + 4] = *(float4*)&a[4];
  __syncthreads();
  float* ts = ws + TSUM_OFF +
              ((size_t)t * ns + (blockIdx.x & (ns - 1))) * COLS;
  int j = tid;
  atomicAdd(&ts[j], part[0][j] + part[1][j] + part[2][j] + part[3][j]);
  j += 256;
  atomicAdd(&ts[j], part[0][j] + part[1][j] + part[2][j] + part[3][j]);
}

// ---- final (iteration 19): preamble sigma_19, fp32 exp, write Q*n ----
__global__ __launch_bounds__(256, 4) void ipot_final_kernel(
    const float* __restrict__ C, float* __restrict__ out,
    const float* __restrict__ ws, int ns) {
  __shared__ float sig[COLS];
  const int tid = threadIdx.x;
  const int wave = tid >> 6;
  const int lane = tid & 63;
  {
    const int t = ITERS - 1;  // 19
    const float* gsp = ws + GSIG_OFF + (size_t)(t - 1) * COLS;
    const float* tb = ws + TSUM_OFF + (size_t)(t - 1) * ns * COLS;
    for (int j = tid; j < COLS; j += 256) {
      float T = 0.0f;
      for (int s = 0; s < ns; ++s) T += tb[s * COLS + j];
      sig[j] = B_M / (gsp[j] * A_M * T + EPS);
    }
  }
  __syncthreads();

  const float4 sA = *(const float4*)&sig[8 * lane];
  const float4 sB = *(const float4*)&sig[8 * lane + 4];
  const int gw = blockIdx.x * WPB + wave;

#pragma unroll
  for (int r = 0; r < RPW; ++r) {
    const int row = gw + r * TW;
    const float4* rp = (const float4*)(C + (size_t)row * COLS);
    float4 c0 = rp[2 * lane];
    float4 c1 = rp[2 * lane + 1];
    float e[8];
    e[0] = exp2f(c0.x * L2E2); e[1] = exp2f(c0.y * L2E2);
    e[2] = exp2f(c0.z * L2E2); e[3] = exp2f(c0.w * L2E2);
    e[4] = exp2f(c1.x * L2E2); e[5] = exp2f(c1.y * L2E2);
    e[6] = exp2f(c1.z * L2E2); e[7] = exp2f(c1.w * L2E2);
    float p = e[0] * sA.x + e[1] * sA.y + e[2] * sA.z + e[3] * sA.w +
              e[4] * sB.x + e[5] * sB.y + e[6] * sB.z + e[7] * sB.w;
#pragma unroll
    for (int off = 32; off; off >>= 1) p += __shfl_xor(p, off, 64);
    const float inv = 1.0f / (p + EPS);
    float4* wp = (float4*)(out + (size_t)row * COLS);
    float4 o0, o1;
    o0.x = e[0] * sA.x * inv; o0.y = e[1] * sA.y * inv;
    o0.z = e[2] * sA.z * inv; o0.w = e[3] * sA.w * inv;
    o1.x = e[4] * sB.x * inv; o1.y = e[5] * sB.y * inv;
    o1.z = e[6] * sB.z * inv; o1.w = e[7] * sB.w * inv;
    wp[2 * lane] = o0;
    wp[2 * lane + 1] = o1;
  }
}

extern "C" void kernel_launch(void* const* d_in, const int* in_sizes, int n_in,
                              void* d_out, int out_size, void* d_ws, size_t ws_size,
                              hipStream_t stream) {
  const float* C = (const float*)d_in[0];
  float* out = (float*)d_out;
  float* ws = (float*)d_ws;

  int ns = 8;
  while (ns > 1 &&
         (size_t)(ITERS + (ITERS - 1) * ns) * COLS * sizeof(float) > ws_size)
    ns >>= 1;

  ipot_zero_kernel<<<256, 256, 0, stream>>>(ws, ns);
  ipot_pass0_kernel<<<BLOCKS, 256, 0, stream>>>(C, out, ws, ns);
  for (int t = 1; t < ITERS - 1; ++t)
    ipot_mid_kernel<<<BLOCKS, 256, 0, stream>>>(out, ws, t, ns);
  ipot_final_kernel<<<BLOCKS, 256, 0, stream>>>(C, out, ws, ns);
}

// Round 6
// 210.138 us; speedup vs baseline: 11.5362x; 1.4434x over previous
//
#include <hip/hip_runtime.h>
#include <cmath>

// IPOT solver: n=32768 rows, K=512 cols, 20 iterations.
// zero -> fused(exp(2C)->bf16 Kb + iteration 0) -> 18 mid passes (bf16) ->
// final pass (fp32 exp recompute, writes Q*n).
// Sigma ordering: pass t's preamble recomputes sigma_t redundantly per block
// from gsig[t-1] + tsum[t-1]; block 0 persists gsig[t]. Kernel boundaries
// order everything (no fences/tickets - round-4 lesson: ~120 us/pass).
// XCD-slab mapping: slab = blockIdx&7 -> contiguous 4096-row (4 MB) panel,
// identical across passes, so each XCD's L2 (4 MB) keeps its panel resident.
// C is streamed with nontemporal loads to avoid evicting Kb from L2.
//
// ws float layout: gsig[20][512] | tsum[19][8][512]  (= 344 KB)

namespace {
constexpr int ROWS = 32768;
constexpr int COLS = 512;
constexpr int ITERS = 20;
constexpr float EPS = 1e-12f;
constexpr float A_M = 1.0f / 32768.0f;
constexpr float B_M = 1.0f / 512.0f;
constexpr float L2E2 = 2.8853900817779268f;  // 2/ln2: exp(2c)=exp2(c*L2E2)
constexpr int BLOCKS = 1024;                 // 4 blocks/CU
constexpr int WPB = 4;                       // waves per block
constexpr int RPW = 8;                       // rows per wave
constexpr int NSH = 8;                       // shadow buffers == #XCDs
constexpr int SLAB_ROWS = ROWS / 8;          // 4096 rows = 4 MB bf16
constexpr int GSIG_OFF = 0;
constexpr int TSUM_OFF = ITERS * COLS;

typedef float f4v __attribute__((ext_vector_type(4)));
}

__device__ __forceinline__ float bflo(unsigned u) {
  union { unsigned i; float f; } v; v.i = u << 16; return v.f;
}
__device__ __forceinline__ float bfhi(unsigned u) {
  union { unsigned i; float f; } v; v.i = u & 0xFFFF0000u; return v.f;
}
__device__ __forceinline__ unsigned f2bf(float f) {
  union { float f; unsigned u; } v; v.f = f;
  return (v.u + 0x7FFFu + ((v.u >> 16) & 1u)) >> 16;
}
__device__ __forceinline__ int wave_row_base(int bid, int wave) {
  const int slab = bid & 7;
  const int idx = bid >> 3;  // 0..127 within slab
  return slab * SLAB_ROWS + (idx * WPB + wave) * RPW;
}

// ---- zero: gsig[0] = 1/K; zero all tsum buffers ----
__global__ __launch_bounds__(256) void ipot_zero_kernel(float* __restrict__ ws) {
  const size_t stride = (size_t)gridDim.x * blockDim.x;
  const size_t gtid = (size_t)blockIdx.x * blockDim.x + threadIdx.x;
  if (gtid < COLS) ws[GSIG_OFF + gtid] = B_M;
  const size_t tsz = (size_t)(ITERS - 1) * NSH * COLS;
  for (size_t i = gtid; i < tsz; i += stride) ws[TSUM_OFF + i] = 0.0f;
}

// ---- pass0: Kb = bf16(exp(2C)) AND iteration 0 (sigma0 uniform) ----
__global__ __launch_bounds__(256, 4) void ipot_pass0_kernel(
    const float* __restrict__ C, float* __restrict__ out,
    float* __restrict__ ws) {
  __shared__ float part[WPB][COLS];
  const int tid = threadIdx.x;
  const int wave = tid >> 6;
  const int lane = tid & 63;
  const int wrow = wave_row_base(blockIdx.x, wave);
  unsigned short* Kb = (unsigned short*)(out + (size_t)ROWS * COLS / 2);

  // stream C rows (nontemporal: one-shot data, keep L2 for Kb)
  f4v c0[RPW], c1[RPW];
#pragma unroll
  for (int r = 0; r < RPW; ++r) {
    const f4v* rp = (const f4v*)(C + (size_t)(wrow + r) * COLS);
    c0[r] = __builtin_nontemporal_load(&rp[2 * lane]);
    c1[r] = __builtin_nontemporal_load(&rp[2 * lane + 1]);
  }

  float p[RPW];
#pragma unroll
  for (int r = 0; r < RPW; ++r) {
    // e in place over c0/c1 (stay live for the column accumulation)
    c0[r].x = exp2f(c0[r].x * L2E2); c0[r].y = exp2f(c0[r].y * L2E2);
    c0[r].z = exp2f(c0[r].z * L2E2); c0[r].w = exp2f(c0[r].w * L2E2);
    c1[r].x = exp2f(c1[r].x * L2E2); c1[r].y = exp2f(c1[r].y * L2E2);
    c1[r].z = exp2f(c1[r].z * L2E2); c1[r].w = exp2f(c1[r].w * L2E2);
    uint4 kp;
    kp.x = f2bf(c0[r].x) | (f2bf(c0[r].y) << 16);
    kp.y = f2bf(c0[r].z) | (f2bf(c0[r].w) << 16);
    kp.z = f2bf(c1[r].x) | (f2bf(c1[r].y) << 16);
    kp.w = f2bf(c1[r].z) | (f2bf(c1[r].w) << 16);
    ((uint4*)(Kb + (size_t)(wrow + r) * COLS))[lane] = kp;
    p[r] = ((c0[r].x + c0[r].y) + (c0[r].z + c0[r].w)) +
           ((c1[r].x + c1[r].y) + (c1[r].z + c1[r].w));
  }
#pragma unroll
  for (int off = 32; off; off >>= 1) {
#pragma unroll
    for (int r = 0; r < RPW; ++r) p[r] += __shfl_xor(p[r], off, 64);
  }
  float a[8] = {0.f, 0.f, 0.f, 0.f, 0.f, 0.f, 0.f, 0.f};
#pragma unroll
  for (int r = 0; r < RPW; ++r) {
    const float inv = 1.0f / (B_M * p[r] + EPS);  // r_i = B*sum(e)
    a[0] += c0[r].x * inv; a[1] += c0[r].y * inv;
    a[2] += c0[r].z * inv; a[3] += c0[r].w * inv;
    a[4] += c1[r].x * inv; a[5] += c1[r].y * inv;
    a[6] += c1[r].z * inv; a[7] += c1[r].w * inv;
  }
  *(float4*)&part[wave][8 * lane] = *(float4*)&a[0];
  *(float4*)&part[wave][8 * lane + 4] = *(float4*)&a[4];
  __syncthreads();
  float* ts = ws + TSUM_OFF + (size_t)(blockIdx.x & 7) * COLS;
  int j = tid;
  atomicAdd(&ts[j], part[0][j] + part[1][j] + part[2][j] + part[3][j]);
  j += 256;
  atomicAdd(&ts[j], part[0][j] + part[1][j] + part[2][j] + part[3][j]);
}

// ---- mid pass t (t=1..18): preamble sigma_t, stream bf16 Kb, tsum[t] ----
__global__ __launch_bounds__(256, 4) void ipot_mid_kernel(
    const float* __restrict__ base, float* __restrict__ ws, int t) {
  __shared__ float sig[COLS];
  __shared__ float part[WPB][COLS];
  const int tid = threadIdx.x;
  const int wave = tid >> 6;
  const int lane = tid & 63;
  const int wrow = wave_row_base(blockIdx.x, wave);
  const unsigned short* Kb =
      (const unsigned short*)(base + (size_t)ROWS * COLS / 2);

  // issue the 8 matrix loads FIRST; preamble latency hides under them
  uint4 kr[RPW];
#pragma unroll
  for (int r = 0; r < RPW; ++r)
    kr[r] = ((const uint4*)(Kb + (size_t)(wrow + r) * COLS))[lane];

  {
    const float* gsp = ws + GSIG_OFF + (size_t)(t - 1) * COLS;
    float* gsc = ws + GSIG_OFF + (size_t)t * COLS;
    const float* tb = ws + TSUM_OFF + (size_t)(t - 1) * NSH * COLS;
    for (int j = tid; j < COLS; j += 256) {
      float T = 0.0f;
#pragma unroll
      for (int s = 0; s < NSH; ++s) T += tb[s * COLS + j];
      const float sv = B_M / (gsp[j] * A_M * T + EPS);
      sig[j] = sv;
      if (blockIdx.x == 0) gsc[j] = sv;
    }
  }
  __syncthreads();

  const float4 sA = *(const float4*)&sig[8 * lane];
  const float4 sB = *(const float4*)&sig[8 * lane + 4];

  float p[RPW];
#pragma unroll
  for (int r = 0; r < RPW; ++r) {
    p[r] = bflo(kr[r].x) * sA.x + bfhi(kr[r].x) * sA.y +
           bflo(kr[r].y) * sA.z + bfhi(kr[r].y) * sA.w +
           bflo(kr[r].z) * sB.x + bfhi(kr[r].z) * sB.y +
           bflo(kr[r].w) * sB.z + bfhi(kr[r].w) * sB.w;
  }
#pragma unroll
  for (int off = 32; off; off >>= 1) {
#pragma unroll
    for (int r = 0; r < RPW; ++r) p[r] += __shfl_xor(p[r], off, 64);
  }
  float a[8] = {0.f, 0.f, 0.f, 0.f, 0.f, 0.f, 0.f, 0.f};
#pragma unroll
  for (int r = 0; r < RPW; ++r) {
    const float inv = 1.0f / (p[r] + EPS);
    a[0] += bflo(kr[r].x) * inv; a[1] += bfhi(kr[r].x) * inv;
    a[2] += bflo(kr[r].y) * inv; a[3] += bfhi(kr[r].y) * inv;
    a[4] += bflo(kr[r].z) * inv; a[5] += bfhi(kr[r].z) * inv;
    a[6] += bflo(kr[r].w) * inv; a[7] += bfhi(kr[r].w) * inv;
  }
  *(float4*)&part[wave][8 * lane] = *(float4*)&a[0];
  *(float4*)&part[wave][8 * lane + 4] = *(float4*)&a[4];
  __syncthreads();
  float* ts = ws + TSUM_OFF +
              ((size_t)t * NSH + (blockIdx.x & 7)) * COLS;
  int j = tid;
  atomicAdd(&ts[j], part[0][j] + part[1][j] + part[2][j] + part[3][j]);
  j += 256;
  atomicAdd(&ts[j], part[0][j] + part[1][j] + part[2][j] + part[3][j]);
}

// ---- final (iteration 19): preamble sigma_19, fp32 exp, write Q*n ----
__global__ __launch_bounds__(256, 4) void ipot_final_kernel(
    const float* __restrict__ C, float* __restrict__ out,
    const float* __restrict__ ws) {
  __shared__ float sig[COLS];
  const int tid = threadIdx.x;
  const int wave = tid >> 6;
  const int lane = tid & 63;
  const int wrow = wave_row_base(blockIdx.x, wave);

  // stream C (nontemporal) — issue before the preamble
  f4v c0[RPW], c1[RPW];
#pragma unroll
  for (int r = 0; r < RPW; ++r) {
    const f4v* rp = (const f4v*)(C + (size_t)(wrow + r) * COLS);
    c0[r] = __builtin_nontemporal_load(&rp[2 * lane]);
    c1[r] = __builtin_nontemporal_load(&rp[2 * lane + 1]);
  }

  {
    const int t = ITERS - 1;  // 19
    const float* gsp = ws + GSIG_OFF + (size_t)(t - 1) * COLS;
    const float* tb = ws + TSUM_OFF + (size_t)(t - 1) * NSH * COLS;
    for (int j = tid; j < COLS; j += 256) {
      float T = 0.0f;
#pragma unroll
      for (int s = 0; s < NSH; ++s) T += tb[s * COLS + j];
      sig[j] = B_M / (gsp[j] * A_M * T + EPS);
    }
  }
  __syncthreads();

  const float4 sA = *(const float4*)&sig[8 * lane];
  const float4 sB = *(const float4*)&sig[8 * lane + 4];

  float p[RPW];
#pragma unroll
  for (int r = 0; r < RPW; ++r) {
    c0[r].x = exp2f(c0[r].x * L2E2); c0[r].y = exp2f(c0[r].y * L2E2);
    c0[r].z = exp2f(c0[r].z * L2E2); c0[r].w = exp2f(c0[r].w * L2E2);
    c1[r].x = exp2f(c1[r].x * L2E2); c1[r].y = exp2f(c1[r].y * L2E2);
    c1[r].z = exp2f(c1[r].z * L2E2); c1[r].w = exp2f(c1[r].w * L2E2);
    p[r] = c0[r].x * sA.x + c0[r].y * sA.y + c0[r].z * sA.z + c0[r].w * sA.w +
           c1[r].x * sB.x + c1[r].y * sB.y + c1[r].z * sB.z + c1[r].w * sB.w;
  }
#pragma unroll
  for (int off = 32; off; off >>= 1) {
#pragma unroll
    for (int r = 0; r < RPW; ++r) p[r] += __shfl_xor(p[r], off, 64);
  }
#pragma unroll
  for (int r = 0; r < RPW; ++r) {
    const float inv = 1.0f / (p[r] + EPS);
    f4v* wp = (f4v*)(out + (size_t)(wrow + r) * COLS);
    f4v o0, o1;
    o0.x = c0[r].x * sA.x * inv; o0.y = c0[r].y * sA.y * inv;
    o0.z = c0[r].z * sA.z * inv; o0.w = c0[r].w * sA.w * inv;
    o1.x = c1[r].x * sB.x * inv; o1.y = c1[r].y * sB.y * inv;
    o1.z = c1[r].z * sB.z * inv; o1.w = c1[r].w * sB.w * inv;
    __builtin_nontemporal_store(o0, &wp[2 * lane]);
    __builtin_nontemporal_store(o1, &wp[2 * lane + 1]);
  }
}

extern "C" void kernel_launch(void* const* d_in, const int* in_sizes, int n_in,
                              void* d_out, int out_size, void* d_ws, size_t ws_size,
                              hipStream_t stream) {
  const float* C = (const float*)d_in[0];
  float* out = (float*)d_out;
  float* ws = (float*)d_ws;

  ipot_zero_kernel<<<128, 256, 0, stream>>>(ws);
  ipot_pass0_kernel<<<BLOCKS, 256, 0, stream>>>(C, out, ws);
  for (int t = 1; t < ITERS - 1; ++t)
    ipot_mid_kernel<<<BLOCKS, 256, 0, stream>>>(out, ws, t);
  ipot_final_kernel<<<BLOCKS, 256, 0, stream>>>(C, out, ws);
}

// Round 7
// 179.157 us; speedup vs baseline: 13.5312x; 1.1729x over previous
//
#include <hip/hip_runtime.h>
#include <cmath>

// IPOT solver: n=32768 rows, K=512 cols, 20 iterations.
// zero -> fused(exp(2C)->bf16 Kb + iteration 0) -> 18 mid passes (bf16) ->
// final pass (fp32 exp recompute, writes Q*n).
// Sigma ordering: pass t's preamble recomputes sigma_t redundantly per block
// from gsig[t-1] + tsum[t-1]; block 0 persists gsig[t]. Kernel boundaries
// order everything (no fences/tickets - round-4 lesson: ~120 us/pass).
// Kb (32 MB, bf16) is L3-resident across all mid passes; C (64 MB) is read
// with PLAIN loads in pass0 so it stays L3-resident for the final pass
// (C + Kb + out = 160 MB < 256 MB Infinity Cache).
// Mid preamble loads are issued BEFORE the Kb loads: vmcnt is ordered, so
// sigma compute then waits only on the preamble loads, overlapping Kb.
//
// ws float layout: gsig[20][512] | tsum[19][8][512]  (= 344 KB)

namespace {
constexpr int ROWS = 32768;
constexpr int COLS = 512;
constexpr int ITERS = 20;
constexpr float EPS = 1e-12f;
constexpr float A_M = 1.0f / 32768.0f;
constexpr float B_M = 1.0f / 512.0f;
constexpr float L2E2 = 2.8853900817779268f;  // 2/ln2: exp(2c)=exp2(c*L2E2)
constexpr int WPB = 4;                       // waves per block
constexpr int NSH = 8;                       // shadow buffers
constexpr int SLAB_ROWS = ROWS / 8;          // 4096 rows = 4 MB bf16
constexpr int GSIG_OFF = 0;
constexpr int TSUM_OFF = ITERS * COLS;
// mid grid: 1024 blocks x 4 waves x 8 rows (proven round 6)
constexpr int MID_BLOCKS = 1024;
constexpr int MID_RPW = 8;
// pass0/final grid: 2048 blocks x 4 waves x 4 rows (8 blocks/CU)
constexpr int BIG_BLOCKS = 2048;
constexpr int BIG_RPW = 4;

typedef float f4v __attribute__((ext_vector_type(4)));
}

__device__ __forceinline__ float bflo(unsigned u) {
  union { unsigned i; float f; } v; v.i = u << 16; return v.f;
}
__device__ __forceinline__ float bfhi(unsigned u) {
  union { unsigned i; float f; } v; v.i = u & 0xFFFF0000u; return v.f;
}
__device__ __forceinline__ unsigned f2bf(float f) {
  union { float f; unsigned u; } v; v.f = f;
  return (v.u + 0x7FFFu + ((v.u >> 16) & 1u)) >> 16;
}
// slab = bid&7 keeps each 4096-row panel on a stable XCD set across passes
__device__ __forceinline__ int row_base_mid(int bid, int wave) {
  return (bid & 7) * SLAB_ROWS + ((bid >> 3) * WPB + wave) * MID_RPW;
}
__device__ __forceinline__ int row_base_big(int bid, int wave) {
  return (bid & 7) * SLAB_ROWS + ((bid >> 3) * WPB + wave) * BIG_RPW;
}

// ---- zero: gsig[0] = 1/K; zero all tsum buffers ----
__global__ __launch_bounds__(256) void ipot_zero_kernel(float* __restrict__ ws) {
  const size_t stride = (size_t)gridDim.x * blockDim.x;
  const size_t gtid = (size_t)blockIdx.x * blockDim.x + threadIdx.x;
  if (gtid < COLS) ws[GSIG_OFF + gtid] = B_M;
  const size_t tsz = (size_t)(ITERS - 1) * NSH * COLS;
  for (size_t i = gtid; i < tsz; i += stride) ws[TSUM_OFF + i] = 0.0f;
}

// ---- pass0: Kb = bf16(exp(2C)) AND iteration 0 (sigma0 uniform) ----
__global__ __launch_bounds__(256, 8) void ipot_pass0_kernel(
    const float* __restrict__ C, float* __restrict__ out,
    float* __restrict__ ws) {
  __shared__ float part[WPB][COLS];
  const int tid = threadIdx.x;
  const int wave = tid >> 6;
  const int lane = tid & 63;
  const int wrow = row_base_big(blockIdx.x, wave);
  unsigned short* Kb = (unsigned short*)(out + (size_t)ROWS * COLS / 2);

  // PLAIN loads: C must land in L3 (final pass re-reads it)
  f4v c0[BIG_RPW], c1[BIG_RPW];
#pragma unroll
  for (int r = 0; r < BIG_RPW; ++r) {
    const f4v* rp = (const f4v*)(C + (size_t)(wrow + r) * COLS);
    c0[r] = rp[2 * lane];
    c1[r] = rp[2 * lane + 1];
  }

  float p[BIG_RPW];
#pragma unroll
  for (int r = 0; r < BIG_RPW; ++r) {
    c0[r].x = exp2f(c0[r].x * L2E2); c0[r].y = exp2f(c0[r].y * L2E2);
    c0[r].z = exp2f(c0[r].z * L2E2); c0[r].w = exp2f(c0[r].w * L2E2);
    c1[r].x = exp2f(c1[r].x * L2E2); c1[r].y = exp2f(c1[r].y * L2E2);
    c1[r].z = exp2f(c1[r].z * L2E2); c1[r].w = exp2f(c1[r].w * L2E2);
    uint4 kp;
    kp.x = f2bf(c0[r].x) | (f2bf(c0[r].y) << 16);
    kp.y = f2bf(c0[r].z) | (f2bf(c0[r].w) << 16);
    kp.z = f2bf(c1[r].x) | (f2bf(c1[r].y) << 16);
    kp.w = f2bf(c1[r].z) | (f2bf(c1[r].w) << 16);
    ((uint4*)(Kb + (size_t)(wrow + r) * COLS))[lane] = kp;
    p[r] = ((c0[r].x + c0[r].y) + (c0[r].z + c0[r].w)) +
           ((c1[r].x + c1[r].y) + (c1[r].z + c1[r].w));
  }
#pragma unroll
  for (int off = 32; off; off >>= 1) {
#pragma unroll
    for (int r = 0; r < BIG_RPW; ++r) p[r] += __shfl_xor(p[r], off, 64);
  }
  float a[8] = {0.f, 0.f, 0.f, 0.f, 0.f, 0.f, 0.f, 0.f};
#pragma unroll
  for (int r = 0; r < BIG_RPW; ++r) {
    const float inv = 1.0f / (B_M * p[r] + EPS);  // r_i = B*sum(e)
    a[0] += c0[r].x * inv; a[1] += c0[r].y * inv;
    a[2] += c0[r].z * inv; a[3] += c0[r].w * inv;
    a[4] += c1[r].x * inv; a[5] += c1[r].y * inv;
    a[6] += c1[r].z * inv; a[7] += c1[r].w * inv;
  }
  *(float4*)&part[wave][8 * lane] = *(float4*)&a[0];
  *(float4*)&part[wave][8 * lane + 4] = *(float4*)&a[4];
  __syncthreads();
  float* ts = ws + TSUM_OFF + (size_t)(blockIdx.x & 7) * COLS;
  int j = tid;
  atomicAdd(&ts[j], part[0][j] + part[1][j] + part[2][j] + part[3][j]);
  j += 256;
  atomicAdd(&ts[j], part[0][j] + part[1][j] + part[2][j] + part[3][j]);
}

// ---- mid pass t (t=1..18): preamble sigma_t, stream bf16 Kb, tsum[t] ----
__global__ __launch_bounds__(256, 4) void ipot_mid_kernel(
    const float* __restrict__ base, float* __restrict__ ws, int t) {
  __shared__ float sig[COLS];
  __shared__ float part[WPB][COLS];
  const int tid = threadIdx.x;
  const int wave = tid >> 6;
  const int lane = tid & 63;
  const int wrow = row_base_mid(blockIdx.x, wave);
  const unsigned short* Kb =
      (const unsigned short*)(base + (size_t)ROWS * COLS / 2);

  // critical-path loads FIRST (vmcnt is ordered: sigma compute then waits
  // only on these 18 loads, with the 8 Kb loads still in flight behind)
  const float* gsp = ws + GSIG_OFF + (size_t)(t - 1) * COLS;
  const float* tb = ws + TSUM_OFF + (size_t)(t - 1) * NSH * COLS;
  float tv0[NSH], tv1[NSH];
#pragma unroll
  for (int s = 0; s < NSH; ++s) {
    tv0[s] = tb[s * COLS + tid];
    tv1[s] = tb[s * COLS + tid + 256];
  }
  const float g0 = gsp[tid];
  const float g1 = gsp[tid + 256];

  uint4 kr[MID_RPW];
#pragma unroll
  for (int r = 0; r < MID_RPW; ++r)
    kr[r] = ((const uint4*)(Kb + (size_t)(wrow + r) * COLS))[lane];

  {
    float T0 = 0.f, T1 = 0.f;
#pragma unroll
    for (int s = 0; s < NSH; ++s) { T0 += tv0[s]; T1 += tv1[s]; }
    const float sv0 = B_M / (g0 * A_M * T0 + EPS);
    const float sv1 = B_M / (g1 * A_M * T1 + EPS);
    sig[tid] = sv0;
    sig[tid + 256] = sv1;
    if (blockIdx.x == 0) {
      float* gsc = ws + GSIG_OFF + (size_t)t * COLS;
      gsc[tid] = sv0;
      gsc[tid + 256] = sv1;
    }
  }
  __syncthreads();

  const float4 sA = *(const float4*)&sig[8 * lane];
  const float4 sB = *(const float4*)&sig[8 * lane + 4];

  float p[MID_RPW];
#pragma unroll
  for (int r = 0; r < MID_RPW; ++r) {
    p[r] = bflo(kr[r].x) * sA.x + bfhi(kr[r].x) * sA.y +
           bflo(kr[r].y) * sA.z + bfhi(kr[r].y) * sA.w +
           bflo(kr[r].z) * sB.x + bfhi(kr[r].z) * sB.y +
           bflo(kr[r].w) * sB.z + bfhi(kr[r].w) * sB.w;
  }
#pragma unroll
  for (int off = 32; off; off >>= 1) {
#pragma unroll
    for (int r = 0; r < MID_RPW; ++r) p[r] += __shfl_xor(p[r], off, 64);
  }
  float a[8] = {0.f, 0.f, 0.f, 0.f, 0.f, 0.f, 0.f, 0.f};
#pragma unroll
  for (int r = 0; r < MID_RPW; ++r) {
    const float inv = 1.0f / (p[r] + EPS);
    a[0] += bflo(kr[r].x) * inv; a[1] += bfhi(kr[r].x) * inv;
    a[2] += bflo(kr[r].y) * inv; a[3] += bfhi(kr[r].y) * inv;
    a[4] += bflo(kr[r].z) * inv; a[5] += bfhi(kr[r].z) * inv;
    a[6] += bflo(kr[r].w) * inv; a[7] += bfhi(kr[r].w) * inv;
  }
  *(float4*)&part[wave][8 * lane] = *(float4*)&a[0];
  *(float4*)&part[wave][8 * lane + 4] = *(float4*)&a[4];
  __syncthreads();
  float* ts = ws + TSUM_OFF +
              ((size_t)t * NSH + (blockIdx.x & 7)) * COLS;
  int j = tid;
  atomicAdd(&ts[j], part[0][j] + part[1][j] + part[2][j] + part[3][j]);
  j += 256;
  atomicAdd(&ts[j], part[0][j] + part[1][j] + part[2][j] + part[3][j]);
}

// ---- final (iteration 19): preamble sigma_19, fp32 exp, write Q*n ----
__global__ __launch_bounds__(256, 8) void ipot_final_kernel(
    const float* __restrict__ C, float* __restrict__ out,
    const float* __restrict__ ws) {
  __shared__ float sig[COLS];
  const int tid = threadIdx.x;
  const int wave = tid >> 6;
  const int lane = tid & 63;
  const int wrow = row_base_big(blockIdx.x, wave);

  // preamble loads first (critical path), then C loads (L3-resident)
  const int t = ITERS - 1;  // 19
  const float* gsp = ws + GSIG_OFF + (size_t)(t - 1) * COLS;
  const float* tb = ws + TSUM_OFF + (size_t)(t - 1) * NSH * COLS;
  float tv0[NSH], tv1[NSH];
#pragma unroll
  for (int s = 0; s < NSH; ++s) {
    tv0[s] = tb[s * COLS + tid];
    tv1[s] = tb[s * COLS + tid + 256];
  }
  const float g0 = gsp[tid];
  const float g1 = gsp[tid + 256];

  f4v c0[BIG_RPW], c1[BIG_RPW];
#pragma unroll
  for (int r = 0; r < BIG_RPW; ++r) {
    const f4v* rp = (const f4v*)(C + (size_t)(wrow + r) * COLS);
    c0[r] = rp[2 * lane];
    c1[r] = rp[2 * lane + 1];
  }

  {
    float T0 = 0.f, T1 = 0.f;
#pragma unroll
    for (int s = 0; s < NSH; ++s) { T0 += tv0[s]; T1 += tv1[s]; }
    sig[tid] = B_M / (g0 * A_M * T0 + EPS);
    sig[tid + 256] = B_M / (g1 * A_M * T1 + EPS);
  }
  __syncthreads();

  const float4 sA = *(const float4*)&sig[8 * lane];
  const float4 sB = *(const float4*)&sig[8 * lane + 4];

  float p[BIG_RPW];
#pragma unroll
  for (int r = 0; r < BIG_RPW; ++r) {
    c0[r].x = exp2f(c0[r].x * L2E2); c0[r].y = exp2f(c0[r].y * L2E2);
    c0[r].z = exp2f(c0[r].z * L2E2); c0[r].w = exp2f(c0[r].w * L2E2);
    c1[r].x = exp2f(c1[r].x * L2E2); c1[r].y = exp2f(c1[r].y * L2E2);
    c1[r].z = exp2f(c1[r].z * L2E2); c1[r].w = exp2f(c1[r].w * L2E2);
    p[r] = c0[r].x * sA.x + c0[r].y * sA.y + c0[r].z * sA.z + c0[r].w * sA.w +
           c1[r].x * sB.x + c1[r].y * sB.y + c1[r].z * sB.z + c1[r].w * sB.w;
  }
#pragma unroll
  for (int off = 32; off; off >>= 1) {
#pragma unroll
    for (int r = 0; r < BIG_RPW; ++r) p[r] += __shfl_xor(p[r], off, 64);
  }
#pragma unroll
  for (int r = 0; r < BIG_RPW; ++r) {
    const float inv = 1.0f / (p[r] + EPS);
    f4v* wp = (f4v*)(out + (size_t)(wrow + r) * COLS);
    f4v o0, o1;
    o0.x = c0[r].x * sA.x * inv; o0.y = c0[r].y * sA.y * inv;
    o0.z = c0[r].z * sA.z * inv; o0.w = c0[r].w * sA.w * inv;
    o1.x = c1[r].x * sB.x * inv; o1.y = c1[r].y * sB.y * inv;
    o1.z = c1[r].z * sB.z * inv; o1.w = c1[r].w * sB.w * inv;
    __builtin_nontemporal_store(o0, &wp[2 * lane]);
    __builtin_nontemporal_store(o1, &wp[2 * lane + 1]);
  }
}

extern "C" void kernel_launch(void* const* d_in, const int* in_sizes, int n_in,
                              void* d_out, int out_size, void* d_ws, size_t ws_size,
                              hipStream_t stream) {
  const float* C = (const float*)d_in[0];
  float* out = (float*)d_out;
  float* ws = (float*)d_ws;

  ipot_zero_kernel<<<128, 256, 0, stream>>>(ws);
  ipot_pass0_kernel<<<BIG_BLOCKS, 256, 0, stream>>>(C, out, ws);
  for (int t = 1; t < ITERS - 1; ++t)
    ipot_mid_kernel<<<MID_BLOCKS, 256, 0, stream>>>(out, ws, t);
  ipot_final_kernel<<<BIG_BLOCKS, 256, 0, stream>>>(C, out, ws);
}